// Round 26
// baseline (820.363 us; speedup 1.0000x reference)
//
#include <hip/hip_runtime.h>

// GCN forward, MI355X (gfx950). Round-25 resubmission. All 25 failures are
// container disk exhaustion at various pipeline stages (harness push, host
// .o write, device link) — the kernel itself has never run nor failed to
// compile for a semantic reason. Pipeline: device-built CSR keyed by dst ->
// (GEMM -> sym-norm aggregation) x2 -> mean-pool -> FC. L1 agg fuses
// bias+ReLU; L2 agg accumulates into the pool buffer; b2 folded into FC.

#define N_NODES 50000
#define N_EDGES 800000
#define ETOT (N_EDGES + N_NODES)
#define D 128
#define NG 64
#define NC 2

__global__ void k_init(int* __restrict__ deg, float* __restrict__ pool,
                       float* __restrict__ cnt, int* __restrict__ cursor) {
    int i = blockIdx.x * 256 + threadIdx.x;
    if (i < N_NODES) deg[i] = 1;
    if (i < NG * D)  pool[i] = 0.f;
    if (i < NG)      cnt[i]  = 0.f;
    if (i == 0)      *cursor = 0;
}

__global__ void k_deg(const int* __restrict__ ei, int* __restrict__ deg) {
    int e = blockIdx.x * 256 + threadIdx.x;
    if (e < N_EDGES) atomicAdd(&deg[ei[N_EDGES + e]], 1);
}

__global__ void k_off(const int* __restrict__ deg, int* __restrict__ cursor,
                      int* __restrict__ off, int* __restrict__ cur,
                      float* __restrict__ dinv, const int* __restrict__ batch,
                      float* __restrict__ cnt) {
    int n = blockIdx.x * 256 + threadIdx.x;
    if (n >= N_NODES) return;
    int dg = deg[n];
    dinv[n] = rsqrtf((float)dg);
    int o = atomicAdd(cursor, dg);
    off[n] = o;
    cur[n] = o;
    atomicAdd(&cnt[batch[n]], 1.f);
}

__global__ void k_scatter(const int* __restrict__ ei, int* __restrict__ cur,
                          int* __restrict__ csr) {
    int e = blockIdx.x * 256 + threadIdx.x;
    if (e >= ETOT) return;
    int s, d2;
    if (e < N_EDGES) { s = ei[e]; d2 = ei[N_EDGES + e]; }
    else             { s = e - N_EDGES; d2 = s; }
    csr[atomicAdd(&cur[d2], 1)] = s;
}

__global__ __launch_bounds__(256) void k_gemm(const float* __restrict__ A,
                                              const float* __restrict__ W,
                                              float* __restrict__ C) {
    __shared__ float As[128][68];
    int tid = threadIdx.x;
    int row0 = blockIdx.x * 64;
    {
        int r  = tid >> 2;
        int f4 = tid & 3;
        int ra = row0 + r; if (ra >= N_NODES) ra = N_NODES - 1;
        const float* arow = A + (size_t)ra * D;
#pragma unroll 1
        for (int i = 0; i < 8; i++) {
            int k0 = f4 * 4 + i * 16;
            float4 v = *(const float4*)(arow + k0);
            As[k0 + 0][r] = v.x;
            As[k0 + 1][r] = v.y;
            As[k0 + 2][r] = v.z;
            As[k0 + 3][r] = v.w;
        }
    }
    __syncthreads();

    int tx = tid & 15;
    int ty = tid >> 4;
    float acc[4][8];
#pragma unroll
    for (int i = 0; i < 4; i++)
#pragma unroll
        for (int j = 0; j < 8; j++) acc[i][j] = 0.f;

    const float* wp = W + tx * 8;
#pragma unroll 4
    for (int k = 0; k < 128; k++) {
        float4 a  = *(const float4*)&As[k][ty * 4];
        float4 b0 = *(const float4*)(wp + k * 128);
        float4 b1 = *(const float4*)(wp + k * 128 + 4);
        float av[4] = {a.x, a.y, a.z, a.w};
        float bv[8] = {b0.x, b0.y, b0.z, b0.w, b1.x, b1.y, b1.z, b1.w};
#pragma unroll
        for (int i = 0; i < 4; i++)
#pragma unroll
            for (int j = 0; j < 8; j++) acc[i][j] = fmaf(av[i], bv[j], acc[i][j]);
    }

#pragma unroll 1
    for (int i = 0; i < 4; i++) {
        int r = row0 + ty * 4 + i;
        if (r < N_NODES) {
            float4 o0 = {acc[i][0], acc[i][1], acc[i][2], acc[i][3]};
            float4 o1 = {acc[i][4], acc[i][5], acc[i][6], acc[i][7]};
            *(float4*)(C + (size_t)r * D + tx * 8)     = o0;
            *(float4*)(C + (size_t)r * D + tx * 8 + 4) = o1;
        }
    }
}

__global__ __launch_bounds__(256) void k_agg(const float* __restrict__ h,
                                             const int* __restrict__ off,
                                             const int* __restrict__ deg,
                                             const int* __restrict__ csr,
                                             const float* __restrict__ dinv,
                                             const float* __restrict__ bias,
                                             const int* __restrict__ batch,
                                             float* __restrict__ outp,
                                             int mode) {
    int n    = (blockIdx.x * 256 + threadIdx.x) >> 6;
    int lane = threadIdx.x & 63;
    if (n >= N_NODES) return;
    int beg = off[n], end = beg + deg[n];
    float dn = dinv[n];
    float ax = 0.f, ay = 0.f;
    const float* hb = h + 2 * lane;
#pragma unroll 1
    for (int p = beg; p < end; p++) {
        int s = csr[p];
        float w = dinv[s] * dn;
        float2 v = *(const float2*)(hb + (size_t)s * D);
        ax = fmaf(w, v.x, ax);
        ay = fmaf(w, v.y, ay);
    }
    if (mode == 0) {
        ax = fmaxf(ax + bias[2 * lane], 0.f);
        ay = fmaxf(ay + bias[2 * lane + 1], 0.f);
        float2 o = {ax, ay};
        *(float2*)(outp + (size_t)n * D + 2 * lane) = o;
    } else {
        float* pp = outp + batch[n] * D + 2 * lane;
        atomicAdd(pp,     ax);
        atomicAdd(pp + 1, ay);
    }
}

__global__ void k_fc(const float* __restrict__ pool, const float* __restrict__ cnt,
                     const float* __restrict__ b2, const float* __restrict__ Wfc,
                     const float* __restrict__ bfc, float* __restrict__ outp) {
    int t = threadIdx.x;
    if (t >= NG * NC) return;
    int g = t >> 1, c = t & 1;
    float cn  = cnt[g];
    float acc = bfc[c];
    if (cn > 0.f) {
        float inv = 1.f / cn;
#pragma unroll 1
        for (int k = 0; k < D; k++)
            acc = fmaf(pool[g * D + k] * inv + b2[k], Wfc[k * NC + c], acc);
    }
    outp[t] = acc;
}

extern "C" void kernel_launch(void* const* d_in, const int* in_sizes, int n_in,
                              void* d_out, int out_size, void* d_ws, size_t ws_size,
                              hipStream_t stream) {
    const float* x     = (const float*)d_in[0];
    const int*   ei    = (const int*)  d_in[1];
    const int*   batch = (const int*)  d_in[2];
    const float* W1    = (const float*)d_in[3];
    const float* b1    = (const float*)d_in[4];
    const float* W2    = (const float*)d_in[5];
    const float* b2    = (const float*)d_in[6];
    const float* Wfc   = (const float*)d_in[7];
    const float* bfc   = (const float*)d_in[8];
    float* out = (float*)d_out;

    char* w = (char*)d_ws;
    auto alloc = [&](size_t bytes) {
        char* p = w;
        w += (bytes + 255) & ~(size_t)255;
        return p;
    };
    int*   deg    = (int*)  alloc((size_t)N_NODES * 4);
    float* dinv   = (float*)alloc((size_t)N_NODES * 4);
    int*   off    = (int*)  alloc((size_t)N_NODES * 4);
    int*   cur    = (int*)  alloc((size_t)N_NODES * 4);
    int*   csr    = (int*)  alloc((size_t)ETOT * 4);
    int*   cursor = (int*)  alloc(256);
    float* hbuf   = (float*)alloc((size_t)N_NODES * D * 4);
    float* gbuf   = (float*)alloc((size_t)N_NODES * D * 4);
    float* pool   = (float*)alloc((size_t)NG * D * 4);
    float* cnt    = (float*)alloc((size_t)NG * 4);

    k_init<<<(N_NODES + 255) / 256, 256, 0, stream>>>(deg, pool, cnt, cursor);
    k_deg<<<(N_EDGES + 255) / 256, 256, 0, stream>>>(ei, deg);
    k_off<<<(N_NODES + 255) / 256, 256, 0, stream>>>(deg, cursor, off, cur, dinv, batch, cnt);
    k_scatter<<<(ETOT + 255) / 256, 256, 0, stream>>>(ei, cur, csr);

    // layer 1: h = x@W1 ; g = relu(agg(h) + b1)
    k_gemm<<<(N_NODES + 63) / 64, 256, 0, stream>>>(x, W1, hbuf);
    k_agg<<<(N_NODES * 64 + 255) / 256, 256, 0, stream>>>(hbuf, off, deg, csr, dinv, b1, batch, gbuf, 0);

    // layer 2: h = g@W2 ; pool += agg(h)
    k_gemm<<<(N_NODES + 63) / 64, 256, 0, stream>>>(gbuf, W2, hbuf);
    k_agg<<<(N_NODES * 64 + 255) / 256, 256, 0, stream>>>(hbuf, off, deg, csr, dinv, nullptr, batch, pool, 1);

    k_fc<<<1, 128, 0, stream>>>(pool, cnt, b2, Wfc, bfc, out);
}

// Round 28
// 504.988 us; speedup vs baseline: 1.6245x; 1.6245x over previous
//
#include <hip/hip_runtime.h>

// GCN forward, MI355X (gfx950). Round 28 (= round-27 kernel resubmitted;
// that round died on the container-disk outage before compiling).
// Baseline (round 26): 820us total, k_off=305us from 50K same-address
// cursor atomics. This version: block-level LDS scan + ONE cursor atomic
// per 256-node block (196 total) + LDS-aggregated per-graph counts.

#define N_NODES 50000
#define N_EDGES 800000
#define ETOT (N_EDGES + N_NODES)
#define D 128
#define NG 64
#define NC 2

__global__ void k_init(int* __restrict__ deg, float* __restrict__ pool,
                       float* __restrict__ cnt, int* __restrict__ cursor) {
    int i = blockIdx.x * 256 + threadIdx.x;
    if (i < N_NODES) deg[i] = 1;
    if (i < NG * D)  pool[i] = 0.f;
    if (i < NG)      cnt[i]  = 0.f;
    if (i == 0)      *cursor = 0;
}

__global__ void k_deg(const int* __restrict__ ei, int* __restrict__ deg) {
    int e = blockIdx.x * 256 + threadIdx.x;
    if (e < N_EDGES) atomicAdd(&deg[ei[N_EDGES + e]], 1);
}

// Block-scan CSR offsets: one cursor atomic per block (196 vs 50000).
__global__ __launch_bounds__(256) void k_off(const int* __restrict__ deg,
                                             int* __restrict__ cursor,
                                             int* __restrict__ off,
                                             int* __restrict__ cur,
                                             float* __restrict__ dinv,
                                             const int* __restrict__ batch,
                                             float* __restrict__ cnt) {
    __shared__ int sh[256];
    __shared__ int base;
    __shared__ float scnt[NG];
    int t = threadIdx.x;
    int n = blockIdx.x * 256 + t;
    if (t < NG) scnt[t] = 0.f;
    int dg = (n < N_NODES) ? deg[n] : 0;
    sh[t] = dg;
    __syncthreads();
    for (int o = 1; o < 256; o <<= 1) {      // Hillis-Steele inclusive scan
        int u = (t >= o) ? sh[t - o] : 0;
        __syncthreads();
        sh[t] += u;
        __syncthreads();
    }
    if (t == 255) base = atomicAdd(cursor, sh[255]);
    __syncthreads();
    if (n < N_NODES) {
        int o2 = base + sh[t] - dg;          // block base + exclusive scan
        off[n] = o2;
        cur[n] = o2;
        dinv[n] = rsqrtf((float)dg);
        atomicAdd(&scnt[batch[n]], 1.f);
    }
    __syncthreads();
    if (t < NG) {
        float v = scnt[t];
        if (v > 0.f) atomicAdd(&cnt[t], v);
    }
}

__global__ void k_scatter(const int* __restrict__ ei, int* __restrict__ cur,
                          int* __restrict__ csr) {
    int e = blockIdx.x * 256 + threadIdx.x;
    if (e >= ETOT) return;
    int s, d2;
    if (e < N_EDGES) { s = ei[e]; d2 = ei[N_EDGES + e]; }
    else             { s = e - N_EDGES; d2 = s; }
    csr[atomicAdd(&cur[d2], 1)] = s;
}

__global__ __launch_bounds__(256) void k_gemm(const float* __restrict__ A,
                                              const float* __restrict__ W,
                                              float* __restrict__ C) {
    __shared__ float As[128][68];
    int tid = threadIdx.x;
    int row0 = blockIdx.x * 64;
    {
        int r  = tid >> 2;
        int f4 = tid & 3;
        int ra = row0 + r; if (ra >= N_NODES) ra = N_NODES - 1;
        const float* arow = A + (size_t)ra * D;
#pragma unroll 1
        for (int i = 0; i < 8; i++) {
            int k0 = f4 * 4 + i * 16;
            float4 v = *(const float4*)(arow + k0);
            As[k0 + 0][r] = v.x;
            As[k0 + 1][r] = v.y;
            As[k0 + 2][r] = v.z;
            As[k0 + 3][r] = v.w;
        }
    }
    __syncthreads();

    int tx = tid & 15;
    int ty = tid >> 4;
    float acc[4][8];
#pragma unroll
    for (int i = 0; i < 4; i++)
#pragma unroll
        for (int j = 0; j < 8; j++) acc[i][j] = 0.f;

    const float* wp = W + tx * 8;
#pragma unroll 4
    for (int k = 0; k < 128; k++) {
        float4 a  = *(const float4*)&As[k][ty * 4];
        float4 b0 = *(const float4*)(wp + k * 128);
        float4 b1 = *(const float4*)(wp + k * 128 + 4);
        float av[4] = {a.x, a.y, a.z, a.w};
        float bv[8] = {b0.x, b0.y, b0.z, b0.w, b1.x, b1.y, b1.z, b1.w};
#pragma unroll
        for (int i = 0; i < 4; i++)
#pragma unroll
            for (int j = 0; j < 8; j++) acc[i][j] = fmaf(av[i], bv[j], acc[i][j]);
    }

#pragma unroll 1
    for (int i = 0; i < 4; i++) {
        int r = row0 + ty * 4 + i;
        if (r < N_NODES) {
            float4 o0 = {acc[i][0], acc[i][1], acc[i][2], acc[i][3]};
            float4 o1 = {acc[i][4], acc[i][5], acc[i][6], acc[i][7]};
            *(float4*)(C + (size_t)r * D + tx * 8)     = o0;
            *(float4*)(C + (size_t)r * D + tx * 8 + 4) = o1;
        }
    }
}

__global__ __launch_bounds__(256) void k_agg(const float* __restrict__ h,
                                             const int* __restrict__ off,
                                             const int* __restrict__ deg,
                                             const int* __restrict__ csr,
                                             const float* __restrict__ dinv,
                                             const float* __restrict__ bias,
                                             const int* __restrict__ batch,
                                             float* __restrict__ outp,
                                             int mode) {
    int n    = (blockIdx.x * 256 + threadIdx.x) >> 6;
    int lane = threadIdx.x & 63;
    if (n >= N_NODES) return;
    int beg = off[n], end = beg + deg[n];
    float dn = dinv[n];
    float ax = 0.f, ay = 0.f;
    const float* hb = h + 2 * lane;
#pragma unroll 1
    for (int p = beg; p < end; p++) {
        int s = csr[p];
        float w = dinv[s] * dn;
        float2 v = *(const float2*)(hb + (size_t)s * D);
        ax = fmaf(w, v.x, ax);
        ay = fmaf(w, v.y, ay);
    }
    if (mode == 0) {
        ax = fmaxf(ax + bias[2 * lane], 0.f);
        ay = fmaxf(ay + bias[2 * lane + 1], 0.f);
        float2 o = {ax, ay};
        *(float2*)(outp + (size_t)n * D + 2 * lane) = o;
    } else {
        float* pp = outp + batch[n] * D + 2 * lane;
        atomicAdd(pp,     ax);
        atomicAdd(pp + 1, ay);
    }
}

__global__ void k_fc(const float* __restrict__ pool, const float* __restrict__ cnt,
                     const float* __restrict__ b2, const float* __restrict__ Wfc,
                     const float* __restrict__ bfc, float* __restrict__ outp) {
    int t = threadIdx.x;
    if (t >= NG * NC) return;
    int g = t >> 1, c = t & 1;
    float cn  = cnt[g];
    float acc = bfc[c];
    if (cn > 0.f) {
        float inv = 1.f / cn;
#pragma unroll 1
        for (int k = 0; k < D; k++)
            acc = fmaf(pool[g * D + k] * inv + b2[k], Wfc[k * NC + c], acc);
    }
    outp[t] = acc;
}

extern "C" void kernel_launch(void* const* d_in, const int* in_sizes, int n_in,
                              void* d_out, int out_size, void* d_ws, size_t ws_size,
                              hipStream_t stream) {
    const float* x     = (const float*)d_in[0];
    const int*   ei    = (const int*)  d_in[1];
    const int*   batch = (const int*)  d_in[2];
    const float* W1    = (const float*)d_in[3];
    const float* b1    = (const float*)d_in[4];
    const float* W2    = (const float*)d_in[5];
    const float* b2    = (const float*)d_in[6];
    const float* Wfc   = (const float*)d_in[7];
    const float* bfc   = (const float*)d_in[8];
    float* out = (float*)d_out;

    char* w = (char*)d_ws;
    auto alloc = [&](size_t bytes) {
        char* p = w;
        w += (bytes + 255) & ~(size_t)255;
        return p;
    };
    int*   deg    = (int*)  alloc((size_t)N_NODES * 4);
    float* dinv   = (float*)alloc((size_t)N_NODES * 4);
    int*   off    = (int*)  alloc((size_t)N_NODES * 4);
    int*   cur    = (int*)  alloc((size_t)N_NODES * 4);
    int*   csr    = (int*)  alloc((size_t)ETOT * 4);
    int*   cursor = (int*)  alloc(256);
    float* hbuf   = (float*)alloc((size_t)N_NODES * D * 4);
    float* gbuf   = (float*)alloc((size_t)N_NODES * D * 4);
    float* pool   = (float*)alloc((size_t)NG * D * 4);
    float* cnt    = (float*)alloc((size_t)NG * 4);

    k_init<<<(N_NODES + 255) / 256, 256, 0, stream>>>(deg, pool, cnt, cursor);
    k_deg<<<(N_EDGES + 255) / 256, 256, 0, stream>>>(ei, deg);
    k_off<<<(N_NODES + 255) / 256, 256, 0, stream>>>(deg, cursor, off, cur, dinv, batch, cnt);
    k_scatter<<<(ETOT + 255) / 256, 256, 0, stream>>>(ei, cur, csr);

    // layer 1: h = x@W1 ; g = relu(agg(h) + b1)
    k_gemm<<<(N_NODES + 63) / 64, 256, 0, stream>>>(x, W1, hbuf);
    k_agg<<<(N_NODES * 64 + 255) / 256, 256, 0, stream>>>(hbuf, off, deg, csr, dinv, b1, batch, gbuf, 0);

    // layer 2: h = g@W2 ; pool += agg(h)
    k_gemm<<<(N_NODES + 63) / 64, 256, 0, stream>>>(gbuf, W2, hbuf);
    k_agg<<<(N_NODES * 64 + 255) / 256, 256, 0, stream>>>(hbuf, off, deg, csr, dinv, nullptr, batch, pool, 1);

    k_fc<<<1, 128, 0, stream>>>(pool, cnt, b2, Wfc, bfc, out);
}

// Round 29
// 425.151 us; speedup vs baseline: 1.9296x; 1.1878x over previous
//
#include <hip/hip_runtime.h>

// GCN forward, MI355X (gfx950). Round 29: k_agg dominates (2x250us of
// 505us) and is latency-bound (VALUBusy 5.5%, 1 outstanding gather/wave —
// my own "#pragma unroll 1"). Fix: manual 4-way unrolled gather with
// prefetched csr/dinv -> 4 outstanding 512B row-gathers per wave.

#define N_NODES 50000
#define N_EDGES 800000
#define ETOT (N_EDGES + N_NODES)
#define D 128
#define NG 64
#define NC 2

__global__ void k_init(int* __restrict__ deg, float* __restrict__ pool,
                       float* __restrict__ cnt, int* __restrict__ cursor) {
    int i = blockIdx.x * 256 + threadIdx.x;
    if (i < N_NODES) deg[i] = 1;
    if (i < NG * D)  pool[i] = 0.f;
    if (i < NG)      cnt[i]  = 0.f;
    if (i == 0)      *cursor = 0;
}

__global__ void k_deg(const int* __restrict__ ei, int* __restrict__ deg) {
    int e = blockIdx.x * 256 + threadIdx.x;
    if (e < N_EDGES) atomicAdd(&deg[ei[N_EDGES + e]], 1);
}

__global__ __launch_bounds__(256) void k_off(const int* __restrict__ deg,
                                             int* __restrict__ cursor,
                                             int* __restrict__ off,
                                             int* __restrict__ cur,
                                             float* __restrict__ dinv,
                                             const int* __restrict__ batch,
                                             float* __restrict__ cnt) {
    __shared__ int sh[256];
    __shared__ int base;
    __shared__ float scnt[NG];
    int t = threadIdx.x;
    int n = blockIdx.x * 256 + t;
    if (t < NG) scnt[t] = 0.f;
    int dg = (n < N_NODES) ? deg[n] : 0;
    sh[t] = dg;
    __syncthreads();
    for (int o = 1; o < 256; o <<= 1) {
        int u = (t >= o) ? sh[t - o] : 0;
        __syncthreads();
        sh[t] += u;
        __syncthreads();
    }
    if (t == 255) base = atomicAdd(cursor, sh[255]);
    __syncthreads();
    if (n < N_NODES) {
        int o2 = base + sh[t] - dg;
        off[n] = o2;
        cur[n] = o2;
        dinv[n] = rsqrtf((float)dg);
        atomicAdd(&scnt[batch[n]], 1.f);
    }
    __syncthreads();
    if (t < NG) {
        float v = scnt[t];
        if (v > 0.f) atomicAdd(&cnt[t], v);
    }
}

__global__ void k_scatter(const int* __restrict__ ei, int* __restrict__ cur,
                          int* __restrict__ csr) {
    int e = blockIdx.x * 256 + threadIdx.x;
    if (e >= ETOT) return;
    int s, d2;
    if (e < N_EDGES) { s = ei[e]; d2 = ei[N_EDGES + e]; }
    else             { s = e - N_EDGES; d2 = s; }
    csr[atomicAdd(&cur[d2], 1)] = s;
}

__global__ __launch_bounds__(256) void k_gemm(const float* __restrict__ A,
                                              const float* __restrict__ W,
                                              float* __restrict__ C) {
    __shared__ float As[128][68];
    int tid = threadIdx.x;
    int row0 = blockIdx.x * 64;
    {
        int r  = tid >> 2;
        int f4 = tid & 3;
        int ra = row0 + r; if (ra >= N_NODES) ra = N_NODES - 1;
        const float* arow = A + (size_t)ra * D;
#pragma unroll 1
        for (int i = 0; i < 8; i++) {
            int k0 = f4 * 4 + i * 16;
            float4 v = *(const float4*)(arow + k0);
            As[k0 + 0][r] = v.x;
            As[k0 + 1][r] = v.y;
            As[k0 + 2][r] = v.z;
            As[k0 + 3][r] = v.w;
        }
    }
    __syncthreads();

    int tx = tid & 15;
    int ty = tid >> 4;
    float acc[4][8];
#pragma unroll
    for (int i = 0; i < 4; i++)
#pragma unroll
        for (int j = 0; j < 8; j++) acc[i][j] = 0.f;

    const float* wp = W + tx * 8;
#pragma unroll 4
    for (int k = 0; k < 128; k++) {
        float4 a  = *(const float4*)&As[k][ty * 4];
        float4 b0 = *(const float4*)(wp + k * 128);
        float4 b1 = *(const float4*)(wp + k * 128 + 4);
        float av[4] = {a.x, a.y, a.z, a.w};
        float bv[8] = {b0.x, b0.y, b0.z, b0.w, b1.x, b1.y, b1.z, b1.w};
#pragma unroll
        for (int i = 0; i < 4; i++)
#pragma unroll
            for (int j = 0; j < 8; j++) acc[i][j] = fmaf(av[i], bv[j], acc[i][j]);
    }

#pragma unroll 1
    for (int i = 0; i < 4; i++) {
        int r = row0 + ty * 4 + i;
        if (r < N_NODES) {
            float4 o0 = {acc[i][0], acc[i][1], acc[i][2], acc[i][3]};
            float4 o1 = {acc[i][4], acc[i][5], acc[i][6], acc[i][7]};
            *(float4*)(C + (size_t)r * D + tx * 8)     = o0;
            *(float4*)(C + (size_t)r * D + tx * 8 + 4) = o1;
        }
    }
}

// One wave per node; lane covers dims 2l,2l+1. 4-way unrolled gather:
// 4 outstanding 512B row reads per wave for memory-level parallelism.
__global__ __launch_bounds__(256) void k_agg(const float* __restrict__ h,
                                             const int* __restrict__ off,
                                             const int* __restrict__ deg,
                                             const int* __restrict__ csr,
                                             const float* __restrict__ dinv,
                                             const float* __restrict__ bias,
                                             const int* __restrict__ batch,
                                             float* __restrict__ outp,
                                             int mode) {
    int n    = (blockIdx.x * 256 + threadIdx.x) >> 6;
    int lane = threadIdx.x & 63;
    if (n >= N_NODES) return;
    int beg = off[n], end = beg + deg[n];
    float dn = dinv[n];
    const float* hb = h + 2 * lane;

    float ax = 0.f, ay = 0.f, bx = 0.f, by = 0.f;
    int p = beg;
    for (; p + 4 <= end; p += 4) {
        int s0 = csr[p], s1 = csr[p + 1], s2 = csr[p + 2], s3 = csr[p + 3];
        float w0 = dinv[s0], w1 = dinv[s1], w2 = dinv[s2], w3 = dinv[s3];
        float2 v0 = *(const float2*)(hb + (size_t)s0 * D);
        float2 v1 = *(const float2*)(hb + (size_t)s1 * D);
        float2 v2 = *(const float2*)(hb + (size_t)s2 * D);
        float2 v3 = *(const float2*)(hb + (size_t)s3 * D);
        ax = fmaf(w0, v0.x, ax); ay = fmaf(w0, v0.y, ay);
        bx = fmaf(w1, v1.x, bx); by = fmaf(w1, v1.y, by);
        ax = fmaf(w2, v2.x, ax); ay = fmaf(w2, v2.y, ay);
        bx = fmaf(w3, v3.x, bx); by = fmaf(w3, v3.y, by);
    }
    for (; p < end; p++) {
        int s = csr[p];
        float w = dinv[s];
        float2 v = *(const float2*)(hb + (size_t)s * D);
        ax = fmaf(w, v.x, ax); ay = fmaf(w, v.y, ay);
    }
    ax = (ax + bx) * dn;
    ay = (ay + by) * dn;

    if (mode == 0) {
        ax = fmaxf(ax + bias[2 * lane], 0.f);
        ay = fmaxf(ay + bias[2 * lane + 1], 0.f);
        float2 o = {ax, ay};
        *(float2*)(outp + (size_t)n * D + 2 * lane) = o;
    } else {
        float* pp = outp + batch[n] * D + 2 * lane;
        atomicAdd(pp,     ax);
        atomicAdd(pp + 1, ay);
    }
}

__global__ void k_fc(const float* __restrict__ pool, const float* __restrict__ cnt,
                     const float* __restrict__ b2, const float* __restrict__ Wfc,
                     const float* __restrict__ bfc, float* __restrict__ outp) {
    int t = threadIdx.x;
    if (t >= NG * NC) return;
    int g = t >> 1, c = t & 1;
    float cn  = cnt[g];
    float acc = bfc[c];
    if (cn > 0.f) {
        float inv = 1.f / cn;
#pragma unroll 1
        for (int k = 0; k < D; k++)
            acc = fmaf(pool[g * D + k] * inv + b2[k], Wfc[k * NC + c], acc);
    }
    outp[t] = acc;
}

extern "C" void kernel_launch(void* const* d_in, const int* in_sizes, int n_in,
                              void* d_out, int out_size, void* d_ws, size_t ws_size,
                              hipStream_t stream) {
    const float* x     = (const float*)d_in[0];
    const int*   ei    = (const int*)  d_in[1];
    const int*   batch = (const int*)  d_in[2];
    const float* W1    = (const float*)d_in[3];
    const float* b1    = (const float*)d_in[4];
    const float* W2    = (const float*)d_in[5];
    const float* b2    = (const float*)d_in[6];
    const float* Wfc   = (const float*)d_in[7];
    const float* bfc   = (const float*)d_in[8];
    float* out = (float*)d_out;

    char* w = (char*)d_ws;
    auto alloc = [&](size_t bytes) {
        char* p = w;
        w += (bytes + 255) & ~(size_t)255;
        return p;
    };
    int*   deg    = (int*)  alloc((size_t)N_NODES * 4);
    float* dinv   = (float*)alloc((size_t)N_NODES * 4);
    int*   off    = (int*)  alloc((size_t)N_NODES * 4);
    int*   cur    = (int*)  alloc((size_t)N_NODES * 4);
    int*   csr    = (int*)  alloc((size_t)ETOT * 4);
    int*   cursor = (int*)  alloc(256);
    float* hbuf   = (float*)alloc((size_t)N_NODES * D * 4);
    float* gbuf   = (float*)alloc((size_t)N_NODES * D * 4);
    float* pool   = (float*)alloc((size_t)NG * D * 4);
    float* cnt    = (float*)alloc((size_t)NG * 4);

    k_init<<<(N_NODES + 255) / 256, 256, 0, stream>>>(deg, pool, cnt, cursor);
    k_deg<<<(N_EDGES + 255) / 256, 256, 0, stream>>>(ei, deg);
    k_off<<<(N_NODES + 255) / 256, 256, 0, stream>>>(deg, cursor, off, cur, dinv, batch, cnt);
    k_scatter<<<(ETOT + 255) / 256, 256, 0, stream>>>(ei, cur, csr);

    // layer 1: h = x@W1 ; g = relu(agg(h) + b1)
    k_gemm<<<(N_NODES + 63) / 64, 256, 0, stream>>>(x, W1, hbuf);
    k_agg<<<(N_NODES * 64 + 255) / 256, 256, 0, stream>>>(hbuf, off, deg, csr, dinv, b1, batch, gbuf, 0);

    // layer 2: h = g@W2 ; pool += agg(h)
    k_gemm<<<(N_NODES + 63) / 64, 256, 0, stream>>>(gbuf, W2, hbuf);
    k_agg<<<(N_NODES * 64 + 255) / 256, 256, 0, stream>>>(hbuf, off, deg, csr, dinv, nullptr, batch, pool, 1);

    k_fc<<<1, 128, 0, stream>>>(pool, cnt, b2, Wfc, bfc, out);
}

// Round 30
// 420.507 us; speedup vs baseline: 1.9509x; 1.0110x over previous
//
#include <hip/hip_runtime.h>

// GCN forward, MI355X (gfx950). Round 30: k_agg still latency-bound
// (VALUBusy 7%, 2.5 TB/s effective gather). Changes: (1) edge weights
// precomputed into csrw[] at scatter time -> aggregation's only random
// load is the h-row itself; (2) 8-way unrolled gather, 4 acc pairs ->
// 8 rows in flight per wave.

#define N_NODES 50000
#define N_EDGES 800000
#define ETOT (N_EDGES + N_NODES)
#define D 128
#define NG 64
#define NC 2

__global__ void k_init(int* __restrict__ deg, float* __restrict__ pool,
                       float* __restrict__ cnt, int* __restrict__ cursor) {
    int i = blockIdx.x * 256 + threadIdx.x;
    if (i < N_NODES) deg[i] = 1;
    if (i < NG * D)  pool[i] = 0.f;
    if (i < NG)      cnt[i]  = 0.f;
    if (i == 0)      *cursor = 0;
}

__global__ void k_deg(const int* __restrict__ ei, int* __restrict__ deg) {
    int e = blockIdx.x * 256 + threadIdx.x;
    if (e < N_EDGES) atomicAdd(&deg[ei[N_EDGES + e]], 1);
}

__global__ __launch_bounds__(256) void k_off(const int* __restrict__ deg,
                                             int* __restrict__ cursor,
                                             int* __restrict__ off,
                                             int* __restrict__ cur,
                                             float* __restrict__ dinv,
                                             const int* __restrict__ batch,
                                             float* __restrict__ cnt) {
    __shared__ int sh[256];
    __shared__ int base;
    __shared__ float scnt[NG];
    int t = threadIdx.x;
    int n = blockIdx.x * 256 + t;
    if (t < NG) scnt[t] = 0.f;
    int dg = (n < N_NODES) ? deg[n] : 0;
    sh[t] = dg;
    __syncthreads();
    for (int o = 1; o < 256; o <<= 1) {
        int u = (t >= o) ? sh[t - o] : 0;
        __syncthreads();
        sh[t] += u;
        __syncthreads();
    }
    if (t == 255) base = atomicAdd(cursor, sh[255]);
    __syncthreads();
    if (n < N_NODES) {
        int o2 = base + sh[t] - dg;
        off[n] = o2;
        cur[n] = o2;
        dinv[n] = rsqrtf((float)dg);
        atomicAdd(&scnt[batch[n]], 1.f);
    }
    __syncthreads();
    if (t < NG) {
        float v = scnt[t];
        if (v > 0.f) atomicAdd(&cnt[t], v);
    }
}

// scatter + fused edge weight: csrw[p] = dinv[src]*dinv[dst]
__global__ void k_scatter(const int* __restrict__ ei, int* __restrict__ cur,
                          const float* __restrict__ dinv,
                          int* __restrict__ csr, float* __restrict__ csrw) {
    int e = blockIdx.x * 256 + threadIdx.x;
    if (e >= ETOT) return;
    int s, d2;
    if (e < N_EDGES) { s = ei[e]; d2 = ei[N_EDGES + e]; }
    else             { s = e - N_EDGES; d2 = s; }
    int p = atomicAdd(&cur[d2], 1);
    csr[p]  = s;
    csrw[p] = dinv[s] * dinv[d2];
}

__global__ __launch_bounds__(256) void k_gemm(const float* __restrict__ A,
                                              const float* __restrict__ W,
                                              float* __restrict__ C) {
    __shared__ float As[128][68];
    int tid = threadIdx.x;
    int row0 = blockIdx.x * 64;
    {
        int r  = tid >> 2;
        int f4 = tid & 3;
        int ra = row0 + r; if (ra >= N_NODES) ra = N_NODES - 1;
        const float* arow = A + (size_t)ra * D;
#pragma unroll 1
        for (int i = 0; i < 8; i++) {
            int k0 = f4 * 4 + i * 16;
            float4 v = *(const float4*)(arow + k0);
            As[k0 + 0][r] = v.x;
            As[k0 + 1][r] = v.y;
            As[k0 + 2][r] = v.z;
            As[k0 + 3][r] = v.w;
        }
    }
    __syncthreads();

    int tx = tid & 15;
    int ty = tid >> 4;
    float acc[4][8];
#pragma unroll
    for (int i = 0; i < 4; i++)
#pragma unroll
        for (int j = 0; j < 8; j++) acc[i][j] = 0.f;

    const float* wp = W + tx * 8;
#pragma unroll 4
    for (int k = 0; k < 128; k++) {
        float4 a  = *(const float4*)&As[k][ty * 4];
        float4 b0 = *(const float4*)(wp + k * 128);
        float4 b1 = *(const float4*)(wp + k * 128 + 4);
        float av[4] = {a.x, a.y, a.z, a.w};
        float bv[8] = {b0.x, b0.y, b0.z, b0.w, b1.x, b1.y, b1.z, b1.w};
#pragma unroll
        for (int i = 0; i < 4; i++)
#pragma unroll
            for (int j = 0; j < 8; j++) acc[i][j] = fmaf(av[i], bv[j], acc[i][j]);
    }

#pragma unroll 1
    for (int i = 0; i < 4; i++) {
        int r = row0 + ty * 4 + i;
        if (r < N_NODES) {
            float4 o0 = {acc[i][0], acc[i][1], acc[i][2], acc[i][3]};
            float4 o1 = {acc[i][4], acc[i][5], acc[i][6], acc[i][7]};
            *(float4*)(C + (size_t)r * D + tx * 8)     = o0;
            *(float4*)(C + (size_t)r * D + tx * 8 + 4) = o1;
        }
    }
}

// One wave per node; lane covers dims 2l,2l+1. 8-way unrolled gather with
// precomputed weights: only the h-row load is random.
__global__ __launch_bounds__(256) void k_agg(const float* __restrict__ h,
                                             const int* __restrict__ off,
                                             const int* __restrict__ deg,
                                             const int* __restrict__ csr,
                                             const float* __restrict__ csrw,
                                             const float* __restrict__ bias,
                                             const int* __restrict__ batch,
                                             float* __restrict__ outp,
                                             int mode) {
    int n    = (blockIdx.x * 256 + threadIdx.x) >> 6;
    int lane = threadIdx.x & 63;
    if (n >= N_NODES) return;
    int beg = off[n], end = beg + deg[n];
    const float* hb = h + 2 * lane;

    float ax = 0.f, ay = 0.f, bx = 0.f, by = 0.f;
    float cx = 0.f, cy = 0.f, dx = 0.f, dy = 0.f;
    int p = beg;
    for (; p + 8 <= end; p += 8) {
        int s0 = csr[p],     s1 = csr[p + 1], s2 = csr[p + 2], s3 = csr[p + 3];
        int s4 = csr[p + 4], s5 = csr[p + 5], s6 = csr[p + 6], s7 = csr[p + 7];
        float w0 = csrw[p],     w1 = csrw[p + 1], w2 = csrw[p + 2], w3 = csrw[p + 3];
        float w4 = csrw[p + 4], w5 = csrw[p + 5], w6 = csrw[p + 6], w7 = csrw[p + 7];
        float2 v0 = *(const float2*)(hb + (size_t)s0 * D);
        float2 v1 = *(const float2*)(hb + (size_t)s1 * D);
        float2 v2 = *(const float2*)(hb + (size_t)s2 * D);
        float2 v3 = *(const float2*)(hb + (size_t)s3 * D);
        float2 v4 = *(const float2*)(hb + (size_t)s4 * D);
        float2 v5 = *(const float2*)(hb + (size_t)s5 * D);
        float2 v6 = *(const float2*)(hb + (size_t)s6 * D);
        float2 v7 = *(const float2*)(hb + (size_t)s7 * D);
        ax = fmaf(w0, v0.x, ax); ay = fmaf(w0, v0.y, ay);
        bx = fmaf(w1, v1.x, bx); by = fmaf(w1, v1.y, by);
        cx = fmaf(w2, v2.x, cx); cy = fmaf(w2, v2.y, cy);
        dx = fmaf(w3, v3.x, dx); dy = fmaf(w3, v3.y, dy);
        ax = fmaf(w4, v4.x, ax); ay = fmaf(w4, v4.y, ay);
        bx = fmaf(w5, v5.x, bx); by = fmaf(w5, v5.y, by);
        cx = fmaf(w6, v6.x, cx); cy = fmaf(w6, v6.y, cy);
        dx = fmaf(w7, v7.x, dx); dy = fmaf(w7, v7.y, dy);
    }
    for (; p < end; p++) {
        int s = csr[p];
        float w = csrw[p];
        float2 v = *(const float2*)(hb + (size_t)s * D);
        ax = fmaf(w, v.x, ax); ay = fmaf(w, v.y, ay);
    }
    float ox = (ax + bx) + (cx + dx);
    float oy = (ay + by) + (cy + dy);

    if (mode == 0) {
        ox = fmaxf(ox + bias[2 * lane], 0.f);
        oy = fmaxf(oy + bias[2 * lane + 1], 0.f);
        float2 o = {ox, oy};
        *(float2*)(outp + (size_t)n * D + 2 * lane) = o;
    } else {
        float* pp = outp + batch[n] * D + 2 * lane;
        atomicAdd(pp,     ox);
        atomicAdd(pp + 1, oy);
    }
}

__global__ void k_fc(const float* __restrict__ pool, const float* __restrict__ cnt,
                     const float* __restrict__ b2, const float* __restrict__ Wfc,
                     const float* __restrict__ bfc, float* __restrict__ outp) {
    int t = threadIdx.x;
    if (t >= NG * NC) return;
    int g = t >> 1, c = t & 1;
    float cn  = cnt[g];
    float acc = bfc[c];
    if (cn > 0.f) {
        float inv = 1.f / cn;
#pragma unroll 1
        for (int k = 0; k < D; k++)
            acc = fmaf(pool[g * D + k] * inv + b2[k], Wfc[k * NC + c], acc);
    }
    outp[t] = acc;
}

extern "C" void kernel_launch(void* const* d_in, const int* in_sizes, int n_in,
                              void* d_out, int out_size, void* d_ws, size_t ws_size,
                              hipStream_t stream) {
    const float* x     = (const float*)d_in[0];
    const int*   ei    = (const int*)  d_in[1];
    const int*   batch = (const int*)  d_in[2];
    const float* W1    = (const float*)d_in[3];
    const float* b1    = (const float*)d_in[4];
    const float* W2    = (const float*)d_in[5];
    const float* b2    = (const float*)d_in[6];
    const float* Wfc   = (const float*)d_in[7];
    const float* bfc   = (const float*)d_in[8];
    float* out = (float*)d_out;

    char* w = (char*)d_ws;
    auto alloc = [&](size_t bytes) {
        char* p = w;
        w += (bytes + 255) & ~(size_t)255;
        return p;
    };
    int*   deg    = (int*)  alloc((size_t)N_NODES * 4);
    float* dinv   = (float*)alloc((size_t)N_NODES * 4);
    int*   off    = (int*)  alloc((size_t)N_NODES * 4);
    int*   cur    = (int*)  alloc((size_t)N_NODES * 4);
    int*   csr    = (int*)  alloc((size_t)ETOT * 4);
    float* csrw   = (float*)alloc((size_t)ETOT * 4);
    int*   cursor = (int*)  alloc(256);
    float* hbuf   = (float*)alloc((size_t)N_NODES * D * 4);
    float* gbuf   = (float*)alloc((size_t)N_NODES * D * 4);
    float* pool   = (float*)alloc((size_t)NG * D * 4);
    float* cnt    = (float*)alloc((size_t)NG * 4);

    k_init<<<(N_NODES + 255) / 256, 256, 0, stream>>>(deg, pool, cnt, cursor);
    k_deg<<<(N_EDGES + 255) / 256, 256, 0, stream>>>(ei, deg);
    k_off<<<(N_NODES + 255) / 256, 256, 0, stream>>>(deg, cursor, off, cur, dinv, batch, cnt);
    k_scatter<<<(ETOT + 255) / 256, 256, 0, stream>>>(ei, cur, dinv, csr, csrw);

    // layer 1: h = x@W1 ; g = relu(agg(h) + b1)
    k_gemm<<<(N_NODES + 63) / 64, 256, 0, stream>>>(x, W1, hbuf);
    k_agg<<<(N_NODES * 64 + 255) / 256, 256, 0, stream>>>(hbuf, off, deg, csr, csrw, b1, batch, gbuf, 0);

    // layer 2: h = g@W2 ; pool += agg(h)
    k_gemm<<<(N_NODES + 63) / 64, 256, 0, stream>>>(gbuf, W2, hbuf);
    k_agg<<<(N_NODES * 64 + 255) / 256, 256, 0, stream>>>(hbuf, off, deg, csr, csrw, nullptr, batch, pool, 1);

    k_fc<<<1, 128, 0, stream>>>(pool, cnt, b2, Wfc, bfc, out);
}

// Round 31
// 409.935 us; speedup vs baseline: 2.0012x; 1.0258x over previous
//
#include <hip/hip_runtime.h>
#include <hip/hip_fp16.h>

// GCN forward, MI355X (gfx950). Round 31: k_agg's wall is the shared
// random-line L2-fill path (4->8 deep MLP changed nothing; 188MB fills at
// ~1TB/s). Fix: fp16 message rows (256B instead of 512B) — halves fill
// bytes, transactions, and working set. Accumulate in f32.

#define N_NODES 50000
#define N_EDGES 800000
#define ETOT (N_EDGES + N_NODES)
#define D 128
#define NG 64
#define NC 2

__global__ void k_init(int* __restrict__ deg, float* __restrict__ pool,
                       float* __restrict__ cnt, int* __restrict__ cursor) {
    int i = blockIdx.x * 256 + threadIdx.x;
    if (i < N_NODES) deg[i] = 1;
    if (i < NG * D)  pool[i] = 0.f;
    if (i < NG)      cnt[i]  = 0.f;
    if (i == 0)      *cursor = 0;
}

__global__ void k_deg(const int* __restrict__ ei, int* __restrict__ deg) {
    int e = blockIdx.x * 256 + threadIdx.x;
    if (e < N_EDGES) atomicAdd(&deg[ei[N_EDGES + e]], 1);
}

__global__ __launch_bounds__(256) void k_off(const int* __restrict__ deg,
                                             int* __restrict__ cursor,
                                             int* __restrict__ off,
                                             int* __restrict__ cur,
                                             float* __restrict__ dinv,
                                             const int* __restrict__ batch,
                                             float* __restrict__ cnt) {
    __shared__ int sh[256];
    __shared__ int base;
    __shared__ float scnt[NG];
    int t = threadIdx.x;
    int n = blockIdx.x * 256 + t;
    if (t < NG) scnt[t] = 0.f;
    int dg = (n < N_NODES) ? deg[n] : 0;
    sh[t] = dg;
    __syncthreads();
    for (int o = 1; o < 256; o <<= 1) {
        int u = (t >= o) ? sh[t - o] : 0;
        __syncthreads();
        sh[t] += u;
        __syncthreads();
    }
    if (t == 255) base = atomicAdd(cursor, sh[255]);
    __syncthreads();
    if (n < N_NODES) {
        int o2 = base + sh[t] - dg;
        off[n] = o2;
        cur[n] = o2;
        dinv[n] = rsqrtf((float)dg);
        atomicAdd(&scnt[batch[n]], 1.f);
    }
    __syncthreads();
    if (t < NG) {
        float v = scnt[t];
        if (v > 0.f) atomicAdd(&cnt[t], v);
    }
}

// scatter + fused edge weight: csrw[p] = dinv[src]*dinv[dst]
__global__ void k_scatter(const int* __restrict__ ei, int* __restrict__ cur,
                          const float* __restrict__ dinv,
                          int* __restrict__ csr, float* __restrict__ csrw) {
    int e = blockIdx.x * 256 + threadIdx.x;
    if (e >= ETOT) return;
    int s, d2;
    if (e < N_EDGES) { s = ei[e]; d2 = ei[N_EDGES + e]; }
    else             { s = e - N_EDGES; d2 = s; }
    int p = atomicAdd(&cur[d2], 1);
    csr[p]  = s;
    csrw[p] = dinv[s] * dinv[d2];
}

// C[N,128] (fp16) = A[N,128] (f32) @ W[128,128] (f32)
__global__ __launch_bounds__(256) void k_gemm(const float* __restrict__ A,
                                              const float* __restrict__ W,
                                              __half* __restrict__ C) {
    __shared__ float As[128][68];
    int tid = threadIdx.x;
    int row0 = blockIdx.x * 64;
    {
        int r  = tid >> 2;
        int f4 = tid & 3;
        int ra = row0 + r; if (ra >= N_NODES) ra = N_NODES - 1;
        const float* arow = A + (size_t)ra * D;
#pragma unroll 1
        for (int i = 0; i < 8; i++) {
            int k0 = f4 * 4 + i * 16;
            float4 v = *(const float4*)(arow + k0);
            As[k0 + 0][r] = v.x;
            As[k0 + 1][r] = v.y;
            As[k0 + 2][r] = v.z;
            As[k0 + 3][r] = v.w;
        }
    }
    __syncthreads();

    int tx = tid & 15;
    int ty = tid >> 4;
    float acc[4][8];
#pragma unroll
    for (int i = 0; i < 4; i++)
#pragma unroll
        for (int j = 0; j < 8; j++) acc[i][j] = 0.f;

    const float* wp = W + tx * 8;
#pragma unroll 4
    for (int k = 0; k < 128; k++) {
        float4 a  = *(const float4*)&As[k][ty * 4];
        float4 b0 = *(const float4*)(wp + k * 128);
        float4 b1 = *(const float4*)(wp + k * 128 + 4);
        float av[4] = {a.x, a.y, a.z, a.w};
        float bv[8] = {b0.x, b0.y, b0.z, b0.w, b1.x, b1.y, b1.z, b1.w};
#pragma unroll
        for (int i = 0; i < 4; i++)
#pragma unroll
            for (int j = 0; j < 8; j++) acc[i][j] = fmaf(av[i], bv[j], acc[i][j]);
    }

#pragma unroll 1
    for (int i = 0; i < 4; i++) {
        int r = row0 + ty * 4 + i;
        if (r < N_NODES) {
            __half2 hh[4];
#pragma unroll
            for (int k2 = 0; k2 < 4; k2++)
                hh[k2] = __floats2half2_rn(acc[i][2 * k2], acc[i][2 * k2 + 1]);
            *(float4*)(C + (size_t)r * D + tx * 8) = *(float4*)hh;  // 16B store of 8 halfs
        }
    }
}

// One wave per node; lane covers dims 2l,2l+1 (__half2 = 4B per lane).
// 8-way unrolled gather; f32 accumulation.
__global__ __launch_bounds__(256) void k_agg(const __half* __restrict__ h,
                                             const int* __restrict__ off,
                                             const int* __restrict__ deg,
                                             const int* __restrict__ csr,
                                             const float* __restrict__ csrw,
                                             const float* __restrict__ bias,
                                             const int* __restrict__ batch,
                                             float* __restrict__ outp,
                                             int mode) {
    int n    = (blockIdx.x * 256 + threadIdx.x) >> 6;
    int lane = threadIdx.x & 63;
    if (n >= N_NODES) return;
    int beg = off[n], end = beg + deg[n];
    const __half2* hb = (const __half2*)h + lane;   // row stride = 64 half2

    float ax = 0.f, ay = 0.f, bx = 0.f, by = 0.f;
    float cx = 0.f, cy = 0.f, dx = 0.f, dy = 0.f;
    int p = beg;
    for (; p + 8 <= end; p += 8) {
        int s0 = csr[p],     s1 = csr[p + 1], s2 = csr[p + 2], s3 = csr[p + 3];
        int s4 = csr[p + 4], s5 = csr[p + 5], s6 = csr[p + 6], s7 = csr[p + 7];
        float w0 = csrw[p],     w1 = csrw[p + 1], w2 = csrw[p + 2], w3 = csrw[p + 3];
        float w4 = csrw[p + 4], w5 = csrw[p + 5], w6 = csrw[p + 6], w7 = csrw[p + 7];
        float2 v0 = __half22float2(hb[(size_t)s0 * 64]);
        float2 v1 = __half22float2(hb[(size_t)s1 * 64]);
        float2 v2 = __half22float2(hb[(size_t)s2 * 64]);
        float2 v3 = __half22float2(hb[(size_t)s3 * 64]);
        float2 v4 = __half22float2(hb[(size_t)s4 * 64]);
        float2 v5 = __half22float2(hb[(size_t)s5 * 64]);
        float2 v6 = __half22float2(hb[(size_t)s6 * 64]);
        float2 v7 = __half22float2(hb[(size_t)s7 * 64]);
        ax = fmaf(w0, v0.x, ax); ay = fmaf(w0, v0.y, ay);
        bx = fmaf(w1, v1.x, bx); by = fmaf(w1, v1.y, by);
        cx = fmaf(w2, v2.x, cx); cy = fmaf(w2, v2.y, cy);
        dx = fmaf(w3, v3.x, dx); dy = fmaf(w3, v3.y, dy);
        ax = fmaf(w4, v4.x, ax); ay = fmaf(w4, v4.y, ay);
        bx = fmaf(w5, v5.x, bx); by = fmaf(w5, v5.y, by);
        cx = fmaf(w6, v6.x, cx); cy = fmaf(w6, v6.y, cy);
        dx = fmaf(w7, v7.x, dx); dy = fmaf(w7, v7.y, dy);
    }
    for (; p < end; p++) {
        int s = csr[p];
        float w = csrw[p];
        float2 v = __half22float2(hb[(size_t)s * 64]);
        ax = fmaf(w, v.x, ax); ay = fmaf(w, v.y, ay);
    }
    float ox = (ax + bx) + (cx + dx);
    float oy = (ay + by) + (cy + dy);

    if (mode == 0) {
        ox = fmaxf(ox + bias[2 * lane], 0.f);
        oy = fmaxf(oy + bias[2 * lane + 1], 0.f);
        float2 o = {ox, oy};
        *(float2*)(outp + (size_t)n * D + 2 * lane) = o;
    } else {
        float* pp = outp + batch[n] * D + 2 * lane;
        atomicAdd(pp,     ox);
        atomicAdd(pp + 1, oy);
    }
}

__global__ void k_fc(const float* __restrict__ pool, const float* __restrict__ cnt,
                     const float* __restrict__ b2, const float* __restrict__ Wfc,
                     const float* __restrict__ bfc, float* __restrict__ outp) {
    int t = threadIdx.x;
    if (t >= NG * NC) return;
    int g = t >> 1, c = t & 1;
    float cn  = cnt[g];
    float acc = bfc[c];
    if (cn > 0.f) {
        float inv = 1.f / cn;
#pragma unroll 1
        for (int k = 0; k < D; k++)
            acc = fmaf(pool[g * D + k] * inv + b2[k], Wfc[k * NC + c], acc);
    }
    outp[t] = acc;
}

extern "C" void kernel_launch(void* const* d_in, const int* in_sizes, int n_in,
                              void* d_out, int out_size, void* d_ws, size_t ws_size,
                              hipStream_t stream) {
    const float* x     = (const float*)d_in[0];
    const int*   ei    = (const int*)  d_in[1];
    const int*   batch = (const int*)  d_in[2];
    const float* W1    = (const float*)d_in[3];
    const float* b1    = (const float*)d_in[4];
    const float* W2    = (const float*)d_in[5];
    const float* b2    = (const float*)d_in[6];
    const float* Wfc   = (const float*)d_in[7];
    const float* bfc   = (const float*)d_in[8];
    float* out = (float*)d_out;

    char* w = (char*)d_ws;
    auto alloc = [&](size_t bytes) {
        char* p = w;
        w += (bytes + 255) & ~(size_t)255;
        return p;
    };
    int*    deg    = (int*)   alloc((size_t)N_NODES * 4);
    float*  dinv   = (float*) alloc((size_t)N_NODES * 4);
    int*    off    = (int*)   alloc((size_t)N_NODES * 4);
    int*    cur    = (int*)   alloc((size_t)N_NODES * 4);
    int*    csr    = (int*)   alloc((size_t)ETOT * 4);
    float*  csrw   = (float*) alloc((size_t)ETOT * 4);
    int*    cursor = (int*)   alloc(256);
    __half* hbuf   = (__half*)alloc((size_t)N_NODES * D * 2);
    float*  gbuf   = (float*) alloc((size_t)N_NODES * D * 4);
    float*  pool   = (float*) alloc((size_t)NG * D * 4);
    float*  cnt    = (float*) alloc((size_t)NG * 4);

    k_init<<<(N_NODES + 255) / 256, 256, 0, stream>>>(deg, pool, cnt, cursor);
    k_deg<<<(N_EDGES + 255) / 256, 256, 0, stream>>>(ei, deg);
    k_off<<<(N_NODES + 255) / 256, 256, 0, stream>>>(deg, cursor, off, cur, dinv, batch, cnt);
    k_scatter<<<(ETOT + 255) / 256, 256, 0, stream>>>(ei, cur, dinv, csr, csrw);

    // layer 1: h = fp16(x@W1) ; g = relu(agg(h) + b1)
    k_gemm<<<(N_NODES + 63) / 64, 256, 0, stream>>>(x, W1, hbuf);
    k_agg<<<(N_NODES * 64 + 255) / 256, 256, 0, stream>>>(hbuf, off, deg, csr, csrw, b1, batch, gbuf, 0);

    // layer 2: h = fp16(g@W2) ; pool += agg(h)
    k_gemm<<<(N_NODES + 63) / 64, 256, 0, stream>>>(gbuf, W2, hbuf);
    k_agg<<<(N_NODES * 64 + 255) / 256, 256, 0, stream>>>(hbuf, off, deg, csr, csrw, nullptr, batch, pool, 1);

    k_fc<<<1, 128, 0, stream>>>(pool, cnt, b2, Wfc, bfc, out);
}

// Round 32
// 277.007 us; speedup vs baseline: 2.9615x; 1.4799x over previous
//
#include <hip/hip_runtime.h>
#include <hip/hip_fp16.h>

// GCN forward, MI355X (gfx950). Round 32: gather wall is byte- and
// MLP-insensitive -> eliminate layer-2's gather algebraically. Pooling is
// linear: pooled[b] = ((sum_j wT[j][b] g[j]) @ W2)/cnt[b] + b2 with
// wT[src][batch[dst]] += norm. Layer 2 becomes a streamed [64x50K]x[50Kx128]
// rank-reduce (g read ONCE, sequential) + tiny head. Layer 1 unchanged
// (fp16 message rows, 8-deep gather).

#define N_NODES 50000
#define N_EDGES 800000
#define ETOT (N_EDGES + N_NODES)
#define D 128
#define NG 64
#define NC 2
#define JT 128
#define NBLK_W ((N_NODES + JT - 1) / JT)      // 391
#define NODES_PAD (NBLK_W * JT)               // 50048
#define WT_F4 (NODES_PAD * NG / 4)            // 800768 float4s
#define Q_F4 (NG * D / 4)                     // 2048 float4s

__global__ void k_init(int* __restrict__ deg, float4* __restrict__ wT4,
                       float4* __restrict__ q4, float* __restrict__ cnt,
                       int* __restrict__ cursor) {
    int i = blockIdx.x * 256 + threadIdx.x;
    float4 z = {0.f, 0.f, 0.f, 0.f};
    if (i < WT_F4) wT4[i] = z;
    if (i < Q_F4)  q4[i] = z;
    if (i < N_NODES) deg[i] = 1;
    if (i < NG)    cnt[i] = 0.f;
    if (i == 0)    *cursor = 0;
}

__global__ void k_deg(const int* __restrict__ ei, int* __restrict__ deg) {
    int e = blockIdx.x * 256 + threadIdx.x;
    if (e < N_EDGES) atomicAdd(&deg[ei[N_EDGES + e]], 1);
}

__global__ __launch_bounds__(256) void k_off(const int* __restrict__ deg,
                                             int* __restrict__ cursor,
                                             int* __restrict__ off,
                                             int* __restrict__ cur,
                                             float* __restrict__ dinv,
                                             const int* __restrict__ batch,
                                             float* __restrict__ cnt) {
    __shared__ int sh[256];
    __shared__ int base;
    __shared__ float scnt[NG];
    int t = threadIdx.x;
    int n = blockIdx.x * 256 + t;
    if (t < NG) scnt[t] = 0.f;
    int dg = (n < N_NODES) ? deg[n] : 0;
    sh[t] = dg;
    __syncthreads();
    for (int o = 1; o < 256; o <<= 1) {
        int u = (t >= o) ? sh[t - o] : 0;
        __syncthreads();
        sh[t] += u;
        __syncthreads();
    }
    if (t == 255) base = atomicAdd(cursor, sh[255]);
    __syncthreads();
    if (n < N_NODES) {
        int o2 = base + sh[t] - dg;
        off[n] = o2;
        cur[n] = o2;
        dinv[n] = rsqrtf((float)dg);
        atomicAdd(&scnt[batch[n]], 1.f);
    }
    __syncthreads();
    if (t < NG) {
        float v = scnt[t];
        if (v > 0.f) atomicAdd(&cnt[t], v);
    }
}

// CSR scatter + edge weight + per-graph source weights wT[s][batch[d]] += w
__global__ void k_scatter(const int* __restrict__ ei, int* __restrict__ cur,
                          const float* __restrict__ dinv,
                          const int* __restrict__ batch,
                          int* __restrict__ csr, float* __restrict__ csrw,
                          float* __restrict__ wT) {
    int e = blockIdx.x * 256 + threadIdx.x;
    if (e >= ETOT) return;
    int s, d2;
    if (e < N_EDGES) { s = ei[e]; d2 = ei[N_EDGES + e]; }
    else             { s = e - N_EDGES; d2 = s; }
    float nw = dinv[s] * dinv[d2];
    int p = atomicAdd(&cur[d2], 1);
    csr[p]  = s;
    csrw[p] = nw;
    atomicAdd(&wT[(size_t)s * NG + batch[d2]], nw);
}

// C[N,128] (fp16) = A[N,128] (f32) @ W[128,128] (f32)
__global__ __launch_bounds__(256) void k_gemm(const float* __restrict__ A,
                                              const float* __restrict__ W,
                                              __half* __restrict__ C) {
    __shared__ float As[128][68];
    int tid = threadIdx.x;
    int row0 = blockIdx.x * 64;
    {
        int r  = tid >> 2;
        int f4 = tid & 3;
        int ra = row0 + r; if (ra >= N_NODES) ra = N_NODES - 1;
        const float* arow = A + (size_t)ra * D;
#pragma unroll 1
        for (int i = 0; i < 8; i++) {
            int k0 = f4 * 4 + i * 16;
            float4 v = *(const float4*)(arow + k0);
            As[k0 + 0][r] = v.x;
            As[k0 + 1][r] = v.y;
            As[k0 + 2][r] = v.z;
            As[k0 + 3][r] = v.w;
        }
    }
    __syncthreads();

    int tx = tid & 15;
    int ty = tid >> 4;
    float acc[4][8];
#pragma unroll
    for (int i = 0; i < 4; i++)
#pragma unroll
        for (int j = 0; j < 8; j++) acc[i][j] = 0.f;

    const float* wp = W + tx * 8;
#pragma unroll 4
    for (int k = 0; k < 128; k++) {
        float4 a  = *(const float4*)&As[k][ty * 4];
        float4 b0 = *(const float4*)(wp + k * 128);
        float4 b1 = *(const float4*)(wp + k * 128 + 4);
        float av[4] = {a.x, a.y, a.z, a.w};
        float bv[8] = {b0.x, b0.y, b0.z, b0.w, b1.x, b1.y, b1.z, b1.w};
#pragma unroll
        for (int i = 0; i < 4; i++)
#pragma unroll
            for (int j = 0; j < 8; j++) acc[i][j] = fmaf(av[i], bv[j], acc[i][j]);
    }

#pragma unroll 1
    for (int i = 0; i < 4; i++) {
        int r = row0 + ty * 4 + i;
        if (r < N_NODES) {
            __half2 hh[4];
#pragma unroll
            for (int k2 = 0; k2 < 4; k2++)
                hh[k2] = __floats2half2_rn(acc[i][2 * k2], acc[i][2 * k2 + 1]);
            *(float4*)(C + (size_t)r * D + tx * 8) = *(float4*)hh;
        }
    }
}

// Layer-1 aggregation: wave per node, lane = half2 (dims 2l,2l+1),
// 8-deep gather, f32 accumulate, fused bias+ReLU.
__global__ __launch_bounds__(256) void k_agg(const __half* __restrict__ h,
                                             const int* __restrict__ off,
                                             const int* __restrict__ deg,
                                             const int* __restrict__ csr,
                                             const float* __restrict__ csrw,
                                             const float* __restrict__ bias,
                                             float* __restrict__ outp) {
    int n    = (blockIdx.x * 256 + threadIdx.x) >> 6;
    int lane = threadIdx.x & 63;
    if (n >= N_NODES) return;
    int beg = off[n], end = beg + deg[n];
    const __half2* hb = (const __half2*)h + lane;

    float ax = 0.f, ay = 0.f, bx = 0.f, by = 0.f;
    float cx = 0.f, cy = 0.f, dx = 0.f, dy = 0.f;
    int p = beg;
    for (; p + 8 <= end; p += 8) {
        int s0 = csr[p],     s1 = csr[p + 1], s2 = csr[p + 2], s3 = csr[p + 3];
        int s4 = csr[p + 4], s5 = csr[p + 5], s6 = csr[p + 6], s7 = csr[p + 7];
        float w0 = csrw[p],     w1 = csrw[p + 1], w2 = csrw[p + 2], w3 = csrw[p + 3];
        float w4 = csrw[p + 4], w5 = csrw[p + 5], w6 = csrw[p + 6], w7 = csrw[p + 7];
        float2 v0 = __half22float2(hb[(size_t)s0 * 64]);
        float2 v1 = __half22float2(hb[(size_t)s1 * 64]);
        float2 v2 = __half22float2(hb[(size_t)s2 * 64]);
        float2 v3 = __half22float2(hb[(size_t)s3 * 64]);
        float2 v4 = __half22float2(hb[(size_t)s4 * 64]);
        float2 v5 = __half22float2(hb[(size_t)s5 * 64]);
        float2 v6 = __half22float2(hb[(size_t)s6 * 64]);
        float2 v7 = __half22float2(hb[(size_t)s7 * 64]);
        ax = fmaf(w0, v0.x, ax); ay = fmaf(w0, v0.y, ay);
        bx = fmaf(w1, v1.x, bx); by = fmaf(w1, v1.y, by);
        cx = fmaf(w2, v2.x, cx); cy = fmaf(w2, v2.y, cy);
        dx = fmaf(w3, v3.x, dx); dy = fmaf(w3, v3.y, dy);
        ax = fmaf(w4, v4.x, ax); ay = fmaf(w4, v4.y, ay);
        bx = fmaf(w5, v5.x, bx); by = fmaf(w5, v5.y, by);
        cx = fmaf(w6, v6.x, cx); cy = fmaf(w6, v6.y, cy);
        dx = fmaf(w7, v7.x, dx); dy = fmaf(w7, v7.y, dy);
    }
    for (; p < end; p++) {
        int s = csr[p];
        float w = csrw[p];
        float2 v = __half22float2(hb[(size_t)s * 64]);
        ax = fmaf(w, v.x, ax); ay = fmaf(w, v.y, ay);
    }
    float ox = (ax + bx) + (cx + dx);
    float oy = (ay + by) + (cy + dy);

    ox = fmaxf(ox + bias[2 * lane], 0.f);
    oy = fmaxf(oy + bias[2 * lane + 1], 0.f);
    float2 o = {ox, oy};
    *(float2*)(outp + (size_t)n * D + 2 * lane) = o;
}

// q[b][d] += sum_{j in tile} wT[j][b] * g[j][d].  wT tile staged in LDS
// (broadcast reads); g streamed coalesced, read exactly once overall.
__global__ __launch_bounds__(256) void k_wgemm(const float* __restrict__ wT,
                                               const float* __restrict__ g,
                                               float* __restrict__ q) {
    __shared__ float ws[JT][NG];      // 32 KB
    int t = threadIdx.x;
    int j0 = blockIdx.x * JT;
    {
        const float4* src = (const float4*)(wT + (size_t)j0 * NG);
        float4* dst = (float4*)ws;
        for (int i = t; i < JT * NG / 4; i += 256) dst[i] = src[i];
    }
    __syncthreads();
    int d  = t & 127;
    int bg = t >> 7;                  // 0/1 -> graphs [bg*32, bg*32+32)
    float acc[32];
#pragma unroll
    for (int i = 0; i < 32; i++) acc[i] = 0.f;
    int jlim = N_NODES - j0; if (jlim > JT) jlim = JT;
    for (int jj = 0; jj < jlim; jj++) {
        float gv = g[(size_t)(j0 + jj) * D + d];
        const float* wrow = &ws[jj][bg * 32];
#pragma unroll
        for (int i = 0; i < 32; i++)
            acc[i] = fmaf(wrow[i], gv, acc[i]);
    }
    float* qb = q + (size_t)(bg * 32) * D + d;
#pragma unroll
    for (int i = 0; i < 32; i++)
        atomicAdd(qb + (size_t)i * D, acc[i]);
}

// pooled[b] = (q[b] @ W2)/cnt[b] + b2 ; out[b] = pooled @ Wfc + bfc
__global__ void k_head(const float* __restrict__ q, const float* __restrict__ cnt,
                       const float* __restrict__ W2, const float* __restrict__ b2,
                       const float* __restrict__ Wfc, const float* __restrict__ bfc,
                       float* __restrict__ outp) {
    __shared__ float pooled[D];
    int b = blockIdx.x, t = threadIdx.x;          // 128 threads
    float cn = cnt[b];
    float pv = 0.f;
    if (cn > 0.f) {
        float acc = 0.f;
        for (int k = 0; k < D; k++)
            acc = fmaf(q[b * D + k], W2[k * D + t], acc);
        pv = acc / cn + b2[t];
    }
    pooled[t] = pv;
    __syncthreads();
    if (t < NC) {
        float acc = bfc[t];
        for (int k = 0; k < D; k++)
            acc = fmaf(pooled[k], Wfc[k * NC + t], acc);
        outp[b * NC + t] = acc;
    }
}

extern "C" void kernel_launch(void* const* d_in, const int* in_sizes, int n_in,
                              void* d_out, int out_size, void* d_ws, size_t ws_size,
                              hipStream_t stream) {
    const float* x     = (const float*)d_in[0];
    const int*   ei    = (const int*)  d_in[1];
    const int*   batch = (const int*)  d_in[2];
    const float* W1    = (const float*)d_in[3];
    const float* b1    = (const float*)d_in[4];
    const float* W2    = (const float*)d_in[5];
    const float* b2    = (const float*)d_in[6];
    const float* Wfc   = (const float*)d_in[7];
    const float* bfc   = (const float*)d_in[8];
    float* out = (float*)d_out;

    char* w = (char*)d_ws;
    auto alloc = [&](size_t bytes) {
        char* p = w;
        w += (bytes + 255) & ~(size_t)255;
        return p;
    };
    int*    deg    = (int*)   alloc((size_t)N_NODES * 4);
    float*  dinv   = (float*) alloc((size_t)N_NODES * 4);
    int*    off    = (int*)   alloc((size_t)N_NODES * 4);
    int*    cur    = (int*)   alloc((size_t)N_NODES * 4);
    int*    csr    = (int*)   alloc((size_t)ETOT * 4);
    float*  csrw   = (float*) alloc((size_t)ETOT * 4);
    int*    cursor = (int*)   alloc(256);
    __half* hbuf   = (__half*)alloc((size_t)N_NODES * D * 2);
    float*  gbuf   = (float*) alloc((size_t)N_NODES * D * 4);
    float*  wT     = (float*) alloc((size_t)NODES_PAD * NG * 4);
    float*  q      = (float*) alloc((size_t)NG * D * 4);
    float*  cnt    = (float*) alloc((size_t)NG * 4);

    k_init<<<(WT_F4 + 255) / 256, 256, 0, stream>>>(deg, (float4*)wT, (float4*)q, cnt, cursor);
    k_deg<<<(N_EDGES + 255) / 256, 256, 0, stream>>>(ei, deg);
    k_off<<<(N_NODES + 255) / 256, 256, 0, stream>>>(deg, cursor, off, cur, dinv, batch, cnt);
    k_scatter<<<(ETOT + 255) / 256, 256, 0, stream>>>(ei, cur, dinv, batch, csr, csrw, wT);

    // layer 1: h = fp16(x@W1) ; g = relu(agg(h) + b1)
    k_gemm<<<(N_NODES + 63) / 64, 256, 0, stream>>>(x, W1, hbuf);
    k_agg<<<(N_NODES * 64 + 255) / 256, 256, 0, stream>>>(hbuf, off, deg, csr, csrw, b1, gbuf);

    // layer 2 (pooled form): q = wT^T @ g ; out = head(q)
    k_wgemm<<<NBLK_W, 256, 0, stream>>>(wT, gbuf, q);
    k_head<<<NG, 128, 0, stream>>>(q, cnt, W2, b2, Wfc, bfc, out);
}